// Round 1
// 118.629 us; speedup vs baseline: 2.9066x; 2.9066x over previous
//
#include <hip/hip_runtime.h>
#include <hip/hip_bf16.h>

typedef short bf16x8 __attribute__((ext_vector_type(8)));
typedef float f32x4  __attribute__((ext_vector_type(4)));
typedef float f32x16 __attribute__((ext_vector_type(16)));

__device__ inline short f2bf(float f) {
    __hip_bfloat16 h = __float2bfloat16(f);
    return *reinterpret_cast<short*>(&h);
}
__device__ inline float bf2f(short s) {
    union { unsigned u; float f; } x;
    x.u = (unsigned)(unsigned short)s << 16;
    return x.f;
}

// ------- pre-pass 1: W1 [256,128] f32 -> W1T [128 col][256 k] bf16 -------
__global__ void __launch_bounds__(256) convert_w1(
    const float* __restrict__ W1, short* __restrict__ w1t)
{
    int i = blockIdx.x * 256 + threadIdx.x;     // 128 blocks -> 32768 threads
    int n = i >> 8, k = i & 255;
    w1t[i] = f2bf(W1[k * 128 + n]);
}

// ------- pre-pass 2: P = src_h @ W1[:128], Q = dst_h @ W1[128:], bf16 out --
// Block 256 thr (4 waves). sW: both 128x128 W1-halves bf16, XOR-swizzled.
// Per block-tile: 128 nodes (wave = 32 nodes), MFMA 32x32x16, K=128.
__global__ void __launch_bounds__(256) precompute_pq(
    const short* __restrict__ w1t,
    const float* __restrict__ src_h, const float* __restrict__ dst_h,
    short* __restrict__ P, short* __restrict__ Q,
    int n_nodes, int n_tiles)
{
    __shared__ short sW[2 * 128 * 128];   // 64 KB

    const int tid = threadIdx.x;
    {   // fill: thread t -> (half H, col cc), 128 shorts, swizzle byte^=(cc&15)<<4
        int H = tid >> 7, cc = tid & 127;
        const short* s = w1t + cc * 256 + H * 128;
        char* dbase = reinterpret_cast<char*>(sW) + ((H * 128 + cc) * 128) * 2;
        const int sw = (cc & 15) << 4;
        #pragma unroll
        for (int ch = 0; ch < 16; ++ch) {
            bf16x8 v = *reinterpret_cast<const bf16x8*>(s + ch * 8);
            *reinterpret_cast<bf16x8*>(dbase + ((ch * 16) ^ sw)) = v;
        }
    }
    __syncthreads();

    const int lane = tid & 63;
    const int wv   = tid >> 6;
    const int l31  = lane & 31;
    const int hg   = lane >> 5;

    for (int t = blockIdx.x; t < n_tiles; t += gridDim.x) {
        const int nodeBase = t * 128 + wv * 32;
        int nl = nodeBase + l31; if (nl >= n_nodes) nl = n_nodes - 1;

        #pragma unroll
        for (int tb = 0; tb < 2; ++tb) {
            const float* x = (tb == 0 ? src_h : dst_h) + (size_t)nl * 128 + hg * 8;
            f32x16 acc[4];
            #pragma unroll
            for (int nf = 0; nf < 4; ++nf) acc[nf] = (f32x16)(0.0f);

            #pragma unroll
            for (int kk = 0; kk < 8; ++kk) {
                f32x4 u = *reinterpret_cast<const f32x4*>(x + kk * 16);
                f32x4 v = *reinterpret_cast<const f32x4*>(x + kk * 16 + 4);
                bf16x8 a;
                #pragma unroll
                for (int j = 0; j < 4; ++j) { a[j] = f2bf(u[j]); a[4 + j] = f2bf(v[j]); }
                #pragma unroll
                for (int nf = 0; nf < 4; ++nf) {
                    int col = nf * 32 + l31;
                    const char* bp = reinterpret_cast<const char*>(sW)
                        + ((tb * 128 + col) * 256)
                        + ((kk * 32 + hg * 16) ^ ((col & 15) << 4));
                    bf16x8 bfr = *reinterpret_cast<const bf16x8*>(bp);
                    acc[nf] = __builtin_amdgcn_mfma_f32_32x32x16_bf16(a, bfr, acc[nf], 0, 0, 0);
                }
            }
            short* T = (tb == 0 ? P : Q);
            #pragma unroll
            for (int nf = 0; nf < 4; ++nf) {
                int col = nf * 32 + l31;
                #pragma unroll
                for (int rg = 0; rg < 16; ++rg) {
                    int row = (rg & 3) + 8 * (rg >> 2) + 4 * hg;
                    int node = nodeBase + row;
                    if (node < n_nodes)
                        T[(size_t)node * 128 + col] = f2bf(acc[nf][rg]);
                }
            }
        }
    }
}

// ------- main: pure gather + elementwise.  16 lanes per node-row.
// Wave batch = 64 edges (4 iters x 16 edges, slots i=0..3, group g=lane>>4).
// Double-buffered row loads, idx prefetched 2 iters ahead, dense 512B stores.
__global__ void __launch_bounds__(256, 4) edge_score(
    const short* __restrict__ P, const short* __restrict__ Q,
    const int* __restrict__ src_idx, const int* __restrict__ dst_idx,
    const float* __restrict__ b1, const float* __restrict__ W2,
    const float* __restrict__ b2,
    float* __restrict__ out, int n_edges, int n_batches)
{
    __shared__ float sOut[4][128];       // per-wave 64 x float2 bounce

    const int tid  = threadIdx.x;
    const int wv   = tid >> 6;
    const int lane = tid & 63;
    const int g    = lane >> 4;          // 0..3  : edge slot-within-quad
    const int c    = lane & 15;          // 0..15 : 8-feature chunk of the row

    float* sOutW = &sOut[wv][0];

    // per-lane constants: this lane's 8 feature channels
    float b1c[8], wdf[8];
    #pragma unroll
    for (int j = 0; j < 8; ++j) {
        int k = c * 8 + j;
        b1c[j] = b1[k];
        wdf[j] = W2[k * 2 + 1] - W2[k * 2 + 0];   // w2[:,1]-w2[:,0]
    }
    const float cdiff = b2[1] - b2[0];

    const int gw = blockIdx.x * 4 + wv;
    const int nw = gridDim.x * 4;

    for (int b = gw; b < n_batches; b += nw) {
        const int ebase = b << 6;

        int    is_[2][4], id_[2][4];
        bf16x8 pv_[2][4], qv_[2][4];

        // prologue: idx(0) -> rows(0) -> idx(1)
        #pragma unroll
        for (int i = 0; i < 4; ++i) {
            int e = ebase + i * 4 + g; if (e >= n_edges) e = n_edges - 1;
            is_[0][i] = src_idx[e]; id_[0][i] = dst_idx[e];
        }
        #pragma unroll
        for (int i = 0; i < 4; ++i) {
            pv_[0][i] = *reinterpret_cast<const bf16x8*>(P + (size_t)is_[0][i] * 128 + c * 8);
            qv_[0][i] = *reinterpret_cast<const bf16x8*>(Q + (size_t)id_[0][i] * 128 + c * 8);
        }
        #pragma unroll
        for (int i = 0; i < 4; ++i) {
            int e = ebase + 16 + i * 4 + g; if (e >= n_edges) e = n_edges - 1;
            is_[1][i] = src_idx[e]; id_[1][i] = dst_idx[e];
        }

        #pragma unroll
        for (int n = 0; n < 4; ++n) {
            const int cur = n & 1, nxt = cur ^ 1;

            // issue rows(n+1) from idx(n+1)
            if (n < 3) {
                #pragma unroll
                for (int i = 0; i < 4; ++i) {
                    pv_[nxt][i] = *reinterpret_cast<const bf16x8*>(P + (size_t)is_[nxt][i] * 128 + c * 8);
                    qv_[nxt][i] = *reinterpret_cast<const bf16x8*>(Q + (size_t)id_[nxt][i] * 128 + c * 8);
                }
            }
            // prefetch idx(n+2) into the just-freed slot
            if (n < 2) {
                #pragma unroll
                for (int i = 0; i < 4; ++i) {
                    int e = ebase + (n + 2) * 16 + i * 4 + g; if (e >= n_edges) e = n_edges - 1;
                    is_[cur][i] = src_idx[e]; id_[cur][i] = dst_idx[e];
                }
            }
            // compute(n)
            #pragma unroll
            for (int i = 0; i < 4; ++i) {
                float a = 0.f;
                #pragma unroll
                for (int j = 0; j < 8; ++j) {
                    float h = fmaxf(bf2f(pv_[cur][i][j]) + bf2f(qv_[cur][i][j]) + b1c[j], 0.f);
                    a = fmaf(h, wdf[j], a);
                }
                a += __shfl_xor(a, 1);
                a += __shfl_xor(a, 2);
                a += __shfl_xor(a, 4);
                a += __shfl_xor(a, 8);
                if (c == i) {
                    float D  = a + cdiff;                      // z1 - z0
                    float p0 = 1.0f / (1.0f + __expf(D));
                    reinterpret_cast<float2*>(sOutW)[n * 16 + i * 4 + g] =
                        make_float2(p0, 1.0f - p0);
                }
            }
        }

        // dense full-wave store: 64 lanes x float2 = 512B contiguous
        asm volatile("s_waitcnt lgkmcnt(0)" ::: "memory");
        {
            float2 r = reinterpret_cast<float2*>(sOutW)[lane];
            int e = ebase + lane;
            if (e < n_edges)
                *reinterpret_cast<float2*>(out + (size_t)e * 2) = r;
        }
    }
}

// ------- fallback (ws too small; not expected to run) -------
__global__ void __launch_bounds__(256) edge_naive(
    const float* __restrict__ src_h, const float* __restrict__ dst_h,
    const int* __restrict__ src_idx, const int* __restrict__ dst_idx,
    const float* __restrict__ W1, const float* __restrict__ b1,
    const float* __restrict__ W2, const float* __restrict__ b2,
    float* __restrict__ out, int n_edges)
{
    int e = blockIdx.x * 256 + threadIdx.x;
    if (e >= n_edges) return;
    const float* xs = src_h + (size_t)src_idx[e] * 128;
    const float* xd = dst_h + (size_t)dst_idx[e] * 128;
    float z0 = b2[0], z1 = b2[1];
    for (int j = 0; j < 128; ++j) {
        float s = b1[j];
        for (int k = 0; k < 128; ++k) s += xs[k] * W1[k * 128 + j];
        for (int k = 0; k < 128; ++k) s += xd[k] * W1[(128 + k) * 128 + j];
        float h = fmaxf(s, 0.f);
        z0 = fmaf(h, W2[j * 2], z0);
        z1 = fmaf(h, W2[j * 2 + 1], z1);
    }
    float p0 = 1.f / (1.f + __expf(z1 - z0));
    out[(size_t)e * 2] = p0; out[(size_t)e * 2 + 1] = 1.f - p0;
}

extern "C" void kernel_launch(void* const* d_in, const int* in_sizes, int n_in,
                              void* d_out, int out_size, void* d_ws, size_t ws_size,
                              hipStream_t stream) {
    const float* src_h   = (const float*)d_in[0];
    const float* dst_h   = (const float*)d_in[1];
    const int*   src_idx = (const int*)d_in[2];
    const int*   dst_idx = (const int*)d_in[3];
    const float* W1      = (const float*)d_in[4];
    const float* b1      = (const float*)d_in[5];
    const float* W2      = (const float*)d_in[6];
    const float* b2      = (const float*)d_in[7];
    float* out = (float*)d_out;

    int n_nodes = in_sizes[0] / 128;
    int n_edges = in_sizes[2];

    size_t tbl_shorts = (size_t)n_nodes * 256;               // P + Q
    size_t need = (tbl_shorts + 256 * 128) * sizeof(short);  // + W1T
    bool use_bf16 = (ws_size >= need);

    if (use_bf16) {
        short* ws  = (short*)d_ws;
        short* Pp  = ws;
        short* Qp  = ws + (size_t)n_nodes * 128;
        short* w1t = ws + tbl_shorts;

        hipLaunchKernelGGL(convert_w1, dim3(128), dim3(256), 0, stream, W1, w1t);

        int pre_tiles = (n_nodes + 127) / 128;
        hipLaunchKernelGGL(precompute_pq, dim3(512), dim3(256), 0, stream,
                           w1t, src_h, dst_h, Pp, Qp, n_nodes, pre_tiles);

        int n_batches = (n_edges + 63) / 64;
        int grid = n_batches < 1024 ? n_batches : 1024;
        hipLaunchKernelGGL(edge_score, dim3(grid), dim3(256), 0, stream,
                           Pp, Qp, src_idx, dst_idx, b1, W2, b2,
                           out, n_edges, n_batches);
    } else {
        hipLaunchKernelGGL(edge_naive, dim3((n_edges + 255) / 256), dim3(256), 0, stream,
                           src_h, dst_h, src_idx, dst_idx,
                           W1, b1, W2, b2, out, n_edges);
    }
}